// Round 15
// baseline (91.931 us; speedup 1.0000x reference)
//
#include <hip/hip_runtime.h>

#define NPIX (512*512)   // 262144
#define NROWS 32         // 8 images x 4 channels
#define NBIN 256         // half-octave bins: code>>6, code = f32bits>>16 (<1.0 => bin<=254)
#define FXS 1048576.0f   // fixed-point sum scale 2^20
#define FXI (1.0/1048576.0)

// RTNE round of f32 to its top-16 bits. Monotone in v for v>=0.
__device__ inline unsigned rtne16_(float v){
  unsigned u = __float_as_uint(v);
  return (u + 0x7FFFu + ((u>>16)&1u)) >> 16;
}

__device__ inline float wredf_(float v){
  #pragma unroll
  for (int o=32;o>0;o>>=1) v += __shfl_down(v, o);
  return v;
}

// ---------------------------------------------------------------------------
// MEGA PASS v4. R14 post-mortem: warm replays = same 66us with FETCH~0 =>
// on-CU bound. Fixes: (1) u64-packed single-atomic histogram (cnt<<40 |
// fx_sum) halves LDS atomic ops + conflicts; (2) reduction restaged through
// the (reused) histogram LDS: 36 wave-ops vs 96 shfl; (3) sched_barrier(0)
// pins all 12 loads before compute (compiler kept VGPR=28 and serialized).
// grid: 8 img x 256 chunks = 2048 blocks (8/CU); 4 consecutive pos/thread.
// segacc: [0]=bce1 [1]=bce2 [2..9]=i1 [10..17]=x1 [18..25]=t1
//         [26..33]=i2 [34..41]=x2 [42..49]=t2   (R10 layout)
// ---------------------------------------------------------------------------
__global__ __launch_bounds__(256, 4) void k_mega(
  const float* __restrict__ us, const float* __restrict__ inputs,
  const float* __restrict__ train_mask, const float* __restrict__ tr_mask,
  const float* __restrict__ label,
  unsigned long long* __restrict__ gh,
  float* __restrict__ pos_cf, float* __restrict__ pos_s,
  float* __restrict__ segacc)
{
  // 16640 B shared: first 2048 u64 = 2-copy histogram; later reused as
  // float part[16][260] (padded) for the scalar reduction.
  __shared__ unsigned long long s_hist[2080];
  float (*s_part)[260] = (float(*)[260])(void*)s_hist;

  int tid = threadIdx.x;
  for (int j=tid;j<2048;j+=256) s_hist[j]=0ull;
  __syncthreads();

  int img = blockIdx.x>>8, chunk = blockIdx.x&255;
  int p0 = chunk*1024 + tid*4;
  size_t gp = (size_t)img*NPIX + p0;
  int cpy = (tid&1)*1024;

  // ---- issue ALL 12 loads, then fence scheduling so they stay hoisted ----
  float4 tm4 = *(const float4*)(train_mask + gp);
  float4 lb4 = *(const float4*)(label + gp);
  const float4* t16 = (const float4*)(tr_mask + gp*4);
  float4 tv0 = t16[0], tv1 = t16[1], tv2 = t16[2], tv3 = t16[3];
  float4 xc0 = *(const float4*)(inputs + ((size_t)(img*4+0))*NPIX + p0);
  float4 xc1 = *(const float4*)(inputs + ((size_t)(img*4+1))*NPIX + p0);
  float4 xc2 = *(const float4*)(inputs + ((size_t)(img*4+2))*NPIX + p0);
  float4 xc3 = *(const float4*)(inputs + ((size_t)(img*4+3))*NPIX + p0);
  float4 ua4 = *(const float4*)(us + ((size_t)img*2  )*NPIX + p0);
  float4 ub4 = *(const float4*)(us + ((size_t)img*2+1)*NPIX + p0);
  __builtin_amdgcn_sched_barrier(0);

  float tm[4] = {tm4.x,tm4.y,tm4.z,tm4.w};
  float lb[4] = {lb4.x,lb4.y,lb4.z,lb4.w};
  float ta_[16] = {tv0.x,tv0.y,tv0.z,tv0.w, tv1.x,tv1.y,tv1.z,tv1.w,
                   tv2.x,tv2.y,tv2.z,tv2.w, tv3.x,tv3.y,tv3.z,tv3.w};
  float xs_[16] = {xc0.x,xc0.y,xc0.z,xc0.w, xc1.x,xc1.y,xc1.z,xc1.w,
                   xc2.x,xc2.y,xc2.z,xc2.w, xc3.x,xc3.y,xc3.z,xc3.w};

  float pcf[4]={0,0,0,0}, ps[4]={0,0,0,0};
  unsigned zc[4]={0,0,0,0};
  float bce1=0.f, i1=0.f, x1s=0.f, t1s=0.f;
  float bce2=0.f, i2=0.f, x2s=0.f, t2s=0.f;

  #pragma unroll
  for (int ch=0; ch<4; ++ch){
    #pragma unroll
    for (int j=0;j<4;++j){
      float t = ta_[j*4+ch];
      float x = xs_[ch*4+j];
      float E = __expf(-fabsf(x));               // native v_exp
      float r = __builtin_amdgcn_rcpf(1.f+E);    // sigmoid(|x|)
      float s = (x>=0.f)? r : 1.f-r;             // sigmoid(x)
      float d = s - t;
      float v = d*d*tm[j];                       // pre_loss in [0,1)
      if (t >= 0.001f){ pcf[ch]+=1.f; ps[ch]+=v; }
      else {
        unsigned code = rtne16_(v);              // <= 0x3F80
        if (code == 0u) zc[ch]++;                // zero-class: registers
        else {
          unsigned fx = (unsigned)(v*FXS + 0.5f);          // <= 2^20
          unsigned long long pack = ((unsigned long long)1<<40) | fx;
          atomicAdd(&s_hist[cpy + ch*NBIN + (int)(code>>6)], pack);
        }
      }
      if (ch==3){                                // seg2: last channel vs label
        float tt = lb[j];
        bce2 += fmaxf(x,0.f) - x*tt + __logf(1.f+E);
        i2 += s*tt; x2s += s; t2s += tt;
      }
    }
  }

  { // seg1: us channels vs one-hot(label)
    float aa[4]={ua4.x,ua4.y,ua4.z,ua4.w};
    float bb[4]={ub4.x,ub4.y,ub4.z,ub4.w};
    #pragma unroll
    for (int j=0;j<4;++j){
      float t1 = lb[j], t0 = 1.f - t1;
      float x0=aa[j], x1=bb[j];
      float E0 = __expf(-fabsf(x0)), E1 = __expf(-fabsf(x1));
      float r0 = __builtin_amdgcn_rcpf(1.f+E0);
      float r1 = __builtin_amdgcn_rcpf(1.f+E1);
      float s0 = (x0>=0.f)? r0 : 1.f-r0;
      float s1 = (x1>=0.f)? r1 : 1.f-r1;
      bce1 += fmaxf(x0,0.f) - x0*t0 + __logf(1.f+E0);
      bce1 += fmaxf(x1,0.f) - x1*t1 + __logf(1.f+E1);
      i1 += s0*t0 + s1*t1; x1s += s0+s1; t1s += t0+t1;
    }
  }

  #pragma unroll
  for (int ch=0;ch<4;++ch)
    if (zc[ch]) atomicAdd(&s_hist[cpy + ch*NBIN],
                          (unsigned long long)zc[ch]<<40);   // bin0: count only
  __syncthreads();

  // flush merged histogram (counts+sums add as disjoint u64 fields)
  for (int j=tid;j<4*NBIN;j+=256){
    unsigned long long c64 = s_hist[j] + s_hist[1024+j];
    if (c64) atomicAdd(&gh[(size_t)(img*4)*NBIN + j], c64);
  }
  __syncthreads();                               // hist LDS now reusable

  // ---- scalar reduction via LDS staging (36 wave-ops vs 96 shfl) ----
  float red[16] = {pcf[0],pcf[1],pcf[2],pcf[3], ps[0],ps[1],ps[2],ps[3],
                   bce1, i1, x1s, t1s, bce2, i2, x2s, t2s};
  #pragma unroll
  for (int q=0;q<16;++q) s_part[q][tid] = red[q];
  __syncthreads();

  int q = tid>>4, g = tid&15;
  float a = 0.f;
  #pragma unroll
  for (int i=0;i<16;++i) a += s_part[q][g*16 + i];
  a += __shfl_down(a, 8);
  a += __shfl_down(a, 4);
  a += __shfl_down(a, 2);
  a += __shfl_down(a, 1);
  if (g == 0){
    if      (q<4)   atomicAdd(&pos_cf[img*4+q], a);
    else if (q<8)   atomicAdd(&pos_s[img*4+q-4], a);
    else if (q==8)  atomicAdd(&segacc[0], a);
    else if (q==9)  atomicAdd(&segacc[2+img], a);
    else if (q==10) atomicAdd(&segacc[10+img], a);
    else if (q==11) atomicAdd(&segacc[18+img], a);
    else if (q==12) atomicAdd(&segacc[1], a);
    else if (q==13) atomicAdd(&segacc[26+img], a);
    else if (q==14) atomicAdd(&segacc[34+img], a);
    else            atomicAdd(&segacc[42+img], a);
  }
}

// ---------------------------------------------------------------------------
// Per-row cut + top-k sum from the 256-bin u64 cnt+sum histogram.
// 32 blocks x 256 thr; thread t owns bin t; parallel SUFFIX scan; owner bin
// applies the order-statistics boundary correction (R14: absmax 0.0).
// ---------------------------------------------------------------------------
__global__ __launch_bounds__(256) void k_items(
  const unsigned long long* __restrict__ gh,
  const float* __restrict__ pos_cf, const float* __restrict__ pos_s,
  float* __restrict__ per_item)
{
  int row = blockIdx.x, tid = threadIdx.x;
  __shared__ unsigned stc[256];
  __shared__ float    sts[256];

  unsigned pc = (unsigned)pos_cf[row];
  float psv = pos_s[row];
  unsigned neg = (unsigned)NPIX - pc, k3 = 3u*pc;
  unsigned k = pc ? (neg<k3?neg:k3) : 100u;     // pos==0 -> top-100 fallback

  if (k == 0u){
    if (tid==0) per_item[row] = psv/(float)(pc?pc:1u);
    return;
  }

  unsigned long long w64 = gh[(size_t)row*NBIN + tid];
  unsigned c0 = (unsigned)(w64 >> 40);
  float    s0 = (float)((double)(w64 & 0xFFFFFFFFFFull) * FXI);
  stc[tid]=c0; sts[tid]=s0;
  __syncthreads();

  // parallel inclusive SUFFIX scan: stc[t] = sum_{t'>=t} cnt[t']
  #pragma unroll
  for (int off=1; off<256; off<<=1){
    unsigned c=0u; float s=0.f;
    if (tid+off < 256){ c=stc[tid+off]; s=sts[tid+off]; }
    __syncthreads();
    stc[tid]+=c; sts[tid]+=s;
    __syncthreads();
  }

  // cut below all counted bins (inside zero-class tail): sum = all nonzeros
  if (tid==0 && stc[0] < k){
    float ssel = sts[0];
    per_item[row] = pc ? (psv/(float)pc + ssel/(float)k) : (ssel/100.f);
    return;
  }

  unsigned above_c = (tid<255)? stc[tid+1] : 0u;
  float    above_s = (tid<255)? sts[tid+1] : 0.f;
  if (above_c < k && stc[tid] >= k){            // owner bin
    unsigned rem = k - above_c;                 // 1 <= rem <= c0
    float mean = s0 / (float)c0;
    float lo = __uint_as_float(((unsigned)tid<<6)<<16);
    float hi = __uint_as_float((((unsigned)tid+1u)<<6)<<16);
    float wdt = hi - lo;
    float mtop = mean + 0.5f*wdt*(1.f - (float)rem/(float)c0);
    mtop = fminf(fmaxf(mtop, lo), hi);          // safety clamp
    float ssel = above_s + (float)rem * mtop;
    per_item[row] = pc ? (psv/(float)pc + ssel/(float)k) : (ssel/100.f);
  }
}

// ---------------------------------------------------------------------------
// Scalar assembly (R10 segacc layout). Output: (h<<16)|h dual f32/bf16.
// ---------------------------------------------------------------------------
__global__ __launch_bounds__(64) void k_scalar(
  const float* __restrict__ per_item, const float* __restrict__ segacc,
  const float* __restrict__ swp, unsigned* __restrict__ out)
{
  int tid = threadIdx.x;
  float v = (tid<NROWS)? per_item[tid] : 0.f;
  v = wredf_(v);
  __shared__ float s_l;
  if (tid==0) s_l = v;
  __syncthreads();
  if (tid != 0) return;

  double lsum = (double)s_l;
  double sw = (double)swp[0];
  double loss = (lsum/8.0)/(2.0*sw*sw + 1e-6) - log(sw);
  double d1=0.0, d2=0.0;
  for (int i=0;i<8;++i){
    d1 += (2.0*(double)segacc[2+i]  + 1e-5)/((double)segacc[10+i] + (double)segacc[18+i] + 1e-5);
    d2 += (2.0*(double)segacc[26+i] + 1e-5)/((double)segacc[34+i] + (double)segacc[42+i] + 1e-5);
  }
  double seg1 = 0.5*((double)segacc[0]/(2.0*8.0*(double)NPIX)) + (1.0 - d1/8.0);
  double seg2 = 0.5*((double)segacc[1]/(8.0*(double)NPIX))     + (1.0 - d2/8.0);
  float tot = (float)(seg1 + seg2 + loss);
  unsigned u = __float_as_uint(tot);
  unsigned h = (u + 0x7FFFu + ((u>>16)&1u)) >> 16;   // RTNE bf16 bits
  out[0] = (h<<16) | h;
}

// ---------------------------------------------------------------------------
extern "C" void kernel_launch(void* const* d_in, const int* in_sizes, int n_in,
                              void* d_out, int out_size, void* d_ws, size_t ws_size,
                              hipStream_t stream)
{
  const float* us         = (const float*)d_in[0];  // (8,2,512,512)
  const float* inputs     = (const float*)d_in[1];  // (8,4,512,512)
  const float* train_mask = (const float*)d_in[2];  // (8,1,512,512)
  const float* tr_mask    = (const float*)d_in[3];  // (8,512,512,4)
  const float* label      = (const float*)d_in[4];  // (8,1,512,512)
  const float* sw         = (const float*)d_in[5];  // (1,)

  char* w = (char*)d_ws;
  size_t off = 0;
  unsigned long long* gh = (unsigned long long*)(w+off); off += (size_t)NROWS*NBIN*8; // 64KB
  float* pos_cf= (float*)(w+off); off += NROWS*4;
  float* pos_s = (float*)(w+off); off += NROWS*4;
  float* segacc= (float*)(w+off); off += 64*4;
  size_t zbytes = off;                               // ~66KB zeroed each call
  float* perit = (float*)(w+off); off += NROWS*4;    // always written

  hipMemsetAsync(w, 0, zbytes, stream);

  k_mega  <<<dim3(2048), dim3(256), 0, stream>>>(us, inputs, train_mask, tr_mask,
                                                 label, gh, pos_cf, pos_s, segacc);
  k_items <<<dim3(NROWS),dim3(256), 0, stream>>>(gh, pos_cf, pos_s, perit);
  k_scalar<<<dim3(1),    dim3(64),  0, stream>>>(perit, segacc, sw, (unsigned*)d_out);
}

// Round 16
// 64.602 us; speedup vs baseline: 1.4230x; 1.4230x over previous
//
#include <hip/hip_runtime.h>

#define NPIX (512*512)   // 262144
#define NROWS 32         // 8 images x 4 channels
#define NBIN 256         // half-octave bins: code>>6 of (f32bits>>16); v<1 => bin<=254

// RTNE round of f32 to its top-16 bits. Monotone in v for v>=0.
__device__ inline unsigned rtne16_(float v){
  unsigned u = __float_as_uint(v);
  return (u + 0x7FFFu + ((u>>16)&1u)) >> 16;
}

__device__ inline float wredf_(float v){
  #pragma unroll
  for (int o=32;o>0;o>>=1) v += __shfl_down(v, o);
  return v;
}

// ---------------------------------------------------------------------------
// MEGA PASS v5 = R14 config (best measured) x2 positions per thread.
// R15 lessons: u64 LDS atomics are SLOWER (u32 only); sched_barrier no help.
// Two R14-identical coalesced batches (h=0,1), so every load instruction is
// lane-stride-16B. Histogram: 2-copy u32 cnt+sum in LDS (R14 exact).
// grid: 8 img x 128 chunks = 1024 blocks; halves flush atomics, init costs,
// and per-block overheads vs R14.
// segacc: [0]=bce1 [1]=bce2 [2..9]=i1 [10..17]=x1 [18..25]=t1
//         [26..33]=i2 [34..41]=x2 [42..49]=t2   (R10/R14 layout)
// ---------------------------------------------------------------------------
__global__ __launch_bounds__(256, 4) void k_mega(
  const float* __restrict__ us, const float* __restrict__ inputs,
  const float* __restrict__ train_mask, const float* __restrict__ tr_mask,
  const float* __restrict__ label,
  unsigned* __restrict__ ghc, float* __restrict__ ghs,
  float* __restrict__ pos_cf, float* __restrict__ pos_s,
  float* __restrict__ segacc)
{
  __shared__ unsigned s_cnt[2*4*NBIN];   // [copy][ch][bin], 8KB
  __shared__ float    s_sum[2*4*NBIN];   // 8KB
  int tid = threadIdx.x;
  for (int j=tid;j<2*4*NBIN;j+=256){ s_cnt[j]=0u; s_sum[j]=0.f; }
  __syncthreads();

  int img = blockIdx.x>>7, chunk = blockIdx.x&127;
  int cpy = (tid&1)*4*NBIN;

  float pcf[4]={0,0,0,0}, ps[4]={0,0,0,0};
  unsigned zc[4]={0,0,0,0};
  float bce1=0.f, i1=0.f, x1s=0.f, t1s=0.f;
  float bce2=0.f, i2=0.f, x2s=0.f, t2s=0.f;

  #pragma unroll
  for (int h=0; h<2; ++h){
    int p0 = chunk*2048 + h*1024 + tid*4;      // coalesced: lane-stride 16B
    size_t gp = (size_t)img*NPIX + p0;

    // ---- 12 independent dwordx4 loads for this batch ----
    float4 tm4 = *(const float4*)(train_mask + gp);
    float4 lb4 = *(const float4*)(label + gp);
    const float4* t16 = (const float4*)(tr_mask + gp*4);
    float4 tv0 = t16[0], tv1 = t16[1], tv2 = t16[2], tv3 = t16[3];
    float4 xc0 = *(const float4*)(inputs + ((size_t)(img*4+0))*NPIX + p0);
    float4 xc1 = *(const float4*)(inputs + ((size_t)(img*4+1))*NPIX + p0);
    float4 xc2 = *(const float4*)(inputs + ((size_t)(img*4+2))*NPIX + p0);
    float4 xc3 = *(const float4*)(inputs + ((size_t)(img*4+3))*NPIX + p0);
    float4 ua4 = *(const float4*)(us + ((size_t)img*2  )*NPIX + p0);
    float4 ub4 = *(const float4*)(us + ((size_t)img*2+1)*NPIX + p0);

    float tm[4] = {tm4.x,tm4.y,tm4.z,tm4.w};
    float lb[4] = {lb4.x,lb4.y,lb4.z,lb4.w};
    float ta_[16] = {tv0.x,tv0.y,tv0.z,tv0.w, tv1.x,tv1.y,tv1.z,tv1.w,
                     tv2.x,tv2.y,tv2.z,tv2.w, tv3.x,tv3.y,tv3.z,tv3.w};
    float xs_[16] = {xc0.x,xc0.y,xc0.z,xc0.w, xc1.x,xc1.y,xc1.z,xc1.w,
                     xc2.x,xc2.y,xc2.z,xc2.w, xc3.x,xc3.y,xc3.z,xc3.w};

    #pragma unroll
    for (int ch=0; ch<4; ++ch){
      #pragma unroll
      for (int j=0;j<4;++j){
        float t = ta_[j*4+ch];
        float x = xs_[ch*4+j];
        float E = __expf(-fabsf(x));               // native v_exp
        float r = __builtin_amdgcn_rcpf(1.f+E);    // sigmoid(|x|)
        float s = (x>=0.f)? r : 1.f-r;             // sigmoid(x)
        float d = s - t;
        float v = d*d*tm[j];                       // pre_loss in [0,1)
        if (t >= 0.001f){ pcf[ch]+=1.f; ps[ch]+=v; }
        else {
          unsigned code = rtne16_(v);              // <= 0x3F80
          if (code == 0u) zc[ch]++;                // zero-class: registers
          else {
            int b = cpy + ch*NBIN + (int)(code>>6);
            atomicAdd(&s_cnt[b], 1u);              // u32 atomics (R15 lesson)
            atomicAdd(&s_sum[b], v);
          }
        }
        if (ch==3){                                // seg2: last ch vs label
          float tt = lb[j];
          bce2 += fmaxf(x,0.f) - x*tt + __logf(1.f+E);
          i2 += s*tt; x2s += s; t2s += tt;
        }
      }
    }

    { // seg1: us channels vs one-hot(label)
      float aa[4]={ua4.x,ua4.y,ua4.z,ua4.w};
      float bb[4]={ub4.x,ub4.y,ub4.z,ub4.w};
      #pragma unroll
      for (int j=0;j<4;++j){
        float t1 = lb[j], t0 = 1.f - t1;
        float x0=aa[j], x1=bb[j];
        float E0 = __expf(-fabsf(x0)), E1 = __expf(-fabsf(x1));
        float r0 = __builtin_amdgcn_rcpf(1.f+E0);
        float r1 = __builtin_amdgcn_rcpf(1.f+E1);
        float s0 = (x0>=0.f)? r0 : 1.f-r0;
        float s1 = (x1>=0.f)? r1 : 1.f-r1;
        bce1 += fmaxf(x0,0.f) - x0*t0 + __logf(1.f+E0);
        bce1 += fmaxf(x1,0.f) - x1*t1 + __logf(1.f+E1);
        i1 += s0*t0 + s1*t1; x1s += s0+s1; t1s += t0+t1;
      }
    }
  }

  #pragma unroll
  for (int ch=0;ch<4;++ch)
    if (zc[ch]) atomicAdd(&s_cnt[cpy + ch*NBIN], zc[ch]);   // bin0: count only

  // 16-scalar block reduction (R14's proven shfl version)
  __shared__ float s_red[4][16];
  float red[16] = {pcf[0],pcf[1],pcf[2],pcf[3], ps[0],ps[1],ps[2],ps[3],
                   bce1, i1, x1s, t1s, bce2, i2, x2s, t2s};
  int wid = tid>>6, lane = tid&63;
  #pragma unroll
  for (int q=0;q<16;++q){
    float r = wredf_(red[q]);
    if (lane==0) s_red[wid][q] = r;
  }
  __syncthreads();
  if (tid < 16){
    float tot = s_red[0][tid]+s_red[1][tid]+s_red[2][tid]+s_red[3][tid];
    int q = tid;
    if      (q<4)   atomicAdd(&pos_cf[img*4+q], tot);
    else if (q<8)   atomicAdd(&pos_s[img*4+q-4], tot);
    else if (q==8)  atomicAdd(&segacc[0], tot);
    else if (q==9)  atomicAdd(&segacc[2+img], tot);
    else if (q==10) atomicAdd(&segacc[10+img], tot);
    else if (q==11) atomicAdd(&segacc[18+img], tot);
    else if (q==12) atomicAdd(&segacc[1], tot);
    else if (q==13) atomicAdd(&segacc[26+img], tot);
    else if (q==14) atomicAdd(&segacc[34+img], tot);
    else            atomicAdd(&segacc[42+img], tot);
  }

  // flush merged histogram partials (<=2048 atomics/block, 128-deep chains)
  for (int j=tid;j<4*NBIN;j+=256){
    unsigned c = s_cnt[j] + s_cnt[4*NBIN+j];
    float    s = s_sum[j] + s_sum[4*NBIN+j];
    int ch = j>>8, bin = j&255;
    if (c)      atomicAdd(&ghc[(img*4+ch)*NBIN + bin], c);
    if (s!=0.f) atomicAdd(&ghs[(img*4+ch)*NBIN + bin], s);
  }
}

// ---------------------------------------------------------------------------
// POST: items + scalar fused in ONE single-block launch (1024 threads).
// Each row owned by a 32-lane group (lane t: bins [t*8, t*8+8)); shfl-based
// suffix scan (width 32); owner lane applies the order-statistics boundary
// correction (R14: absmax 0.0). Then wave 0 assembles the scalar.
// Output: (h<<16)|h dual f32/bf16 encoding (proven).
// ---------------------------------------------------------------------------
__global__ __launch_bounds__(1024) void k_post(
  const unsigned* __restrict__ ghc, const float* __restrict__ ghs,
  const float* __restrict__ pos_cf, const float* __restrict__ pos_s,
  const float* __restrict__ segacc, const float* __restrict__ swp,
  unsigned* __restrict__ out)
{
  __shared__ float s_items[NROWS];
  int tid = threadIdx.x;
  int row = tid >> 5, t32 = tid & 31;

  {
    unsigned pc = (unsigned)pos_cf[row];
    float psv = pos_s[row];
    unsigned neg = (unsigned)NPIX - pc, k3 = 3u*pc;
    unsigned k = pc ? (neg<k3?neg:k3) : 100u;   // pos==0 -> top-100 fallback

    // per-lane bin segment
    unsigned bc[8]; float bsum=0.f; unsigned bcnt=0u;
    #pragma unroll
    for (int j=0;j<8;++j){
      int b = row*NBIN + t32*8 + j;
      bc[j] = ghc[b];
      bcnt += bc[j];
      bsum += ghs[b];
    }
    // inclusive SUFFIX scan across the 32-lane group
    unsigned suf_c = bcnt; float suf_s = bsum;
    #pragma unroll
    for (int o=1;o<32;o<<=1){
      unsigned c2 = __shfl_down(suf_c, o, 32);
      float    s2 = __shfl_down(suf_s, o, 32);
      if (t32 + o < 32){ suf_c += c2; suf_s += s2; }
    }
    unsigned nxt_c = __shfl_down(suf_c, 1, 32);
    float    nxt_s = __shfl_down(suf_s, 1, 32);
    if (t32 == 31){ nxt_c = 0u; nxt_s = 0.f; }

    if (k == 0u){
      if (t32==0) s_items[row] = psv/(float)(pc?pc:1u);
    } else if (t32==0 && suf_c < k){
      // cut in zero-class tail: top-k sum = all nonzero negs
      float ssel = suf_s;
      s_items[row] = pc ? (psv/(float)pc + ssel/(float)k) : (ssel/100.f);
    } else if (nxt_c < k && suf_c >= k){        // owner lane
      unsigned cnt = nxt_c; float sum = nxt_s;
      int bin = -1; unsigned c0 = 1u; float sown = 0.f;
      for (int j=7;j>=0;--j){
        unsigned c = bc[j];
        if (!c) continue;
        if (cnt + c >= k){ bin = t32*8 + j; c0 = c;
                           sown = ghs[row*NBIN + bin]; break; }
        cnt += c; sum += ghs[row*NBIN + t32*8 + j];
      }
      unsigned rem = k - cnt;                   // 1 <= rem <= c0
      float mean = sown / (float)c0;
      float lo = __uint_as_float(((unsigned)bin<<6)<<16);
      float hi = __uint_as_float((((unsigned)bin+1u)<<6)<<16);
      float wdt = hi - lo;
      float mtop = mean + 0.5f*wdt*(1.f - (float)rem/(float)c0);
      mtop = fminf(fmaxf(mtop, lo), hi);        // safety clamp
      float ssel = sum + (float)rem * mtop;
      s_items[row] = pc ? (psv/(float)pc + ssel/(float)k) : (ssel/100.f);
    }
  }
  __syncthreads();
  if (tid >= 64) return;

  // ---- scalar assembly on wave 0 ----
  float v = (tid<NROWS)? s_items[tid] : 0.f;
  v = wredf_(v);                                 // lane 0 gets total
  if (tid != 0) return;

  double lsum = (double)v;
  double sw = (double)swp[0];
  double loss = (lsum/8.0)/(2.0*sw*sw + 1e-6) - log(sw);
  double d1=0.0, d2=0.0;
  for (int i=0;i<8;++i){
    d1 += (2.0*(double)segacc[2+i]  + 1e-5)/((double)segacc[10+i] + (double)segacc[18+i] + 1e-5);
    d2 += (2.0*(double)segacc[26+i] + 1e-5)/((double)segacc[34+i] + (double)segacc[42+i] + 1e-5);
  }
  double seg1 = 0.5*((double)segacc[0]/(2.0*8.0*(double)NPIX)) + (1.0 - d1/8.0);
  double seg2 = 0.5*((double)segacc[1]/(8.0*(double)NPIX))     + (1.0 - d2/8.0);
  float tot = (float)(seg1 + seg2 + loss);
  unsigned u = __float_as_uint(tot);
  unsigned h = (u + 0x7FFFu + ((u>>16)&1u)) >> 16;   // RTNE bf16 bits
  out[0] = (h<<16) | h;                               // dual f32/bf16 encoding
}

// ---------------------------------------------------------------------------
extern "C" void kernel_launch(void* const* d_in, const int* in_sizes, int n_in,
                              void* d_out, int out_size, void* d_ws, size_t ws_size,
                              hipStream_t stream)
{
  const float* us         = (const float*)d_in[0];  // (8,2,512,512)
  const float* inputs     = (const float*)d_in[1];  // (8,4,512,512)
  const float* train_mask = (const float*)d_in[2];  // (8,1,512,512)
  const float* tr_mask    = (const float*)d_in[3];  // (8,512,512,4)
  const float* label      = (const float*)d_in[4];  // (8,1,512,512)
  const float* sw         = (const float*)d_in[5];  // (1,)

  char* w = (char*)d_ws;
  size_t off = 0;
  unsigned* ghc   = (unsigned*)(w+off); off += (size_t)NROWS*NBIN*4;  // 32KB
  float*    ghs   = (float*)(w+off);    off += (size_t)NROWS*NBIN*4;  // 32KB
  float*    pos_cf= (float*)(w+off);    off += NROWS*4;
  float*    pos_s = (float*)(w+off);    off += NROWS*4;
  float*    segacc= (float*)(w+off);    off += 64*4;
  size_t zbytes = off;                               // ~66KB zeroed each call

  hipMemsetAsync(w, 0, zbytes, stream);

  k_mega <<<dim3(1024), dim3(256),  0, stream>>>(us, inputs, train_mask, tr_mask,
                                                 label, ghc, ghs,
                                                 pos_cf, pos_s, segacc);
  k_post <<<dim3(1),    dim3(1024), 0, stream>>>(ghc, ghs, pos_cf, pos_s,
                                                 segacc, sw, (unsigned*)d_out);
}

// Round 17
// 60.564 us; speedup vs baseline: 1.5179x; 1.0667x over previous
//
#include <hip/hip_runtime.h>

#define NPIX (512*512)   // 262144
#define NROWS 32         // 8 images x 4 channels
#define NBIN 256         // half-octave bins: code>>6 of (f32bits>>16); v<1 => bin<=254

// RTNE round of f32 to its top-16 bits. Monotone in v for v>=0.
__device__ inline unsigned rtne16_(float v){
  unsigned u = __float_as_uint(v);
  return (u + 0x7FFFu + ((u>>16)&1u)) >> 16;
}

__device__ inline float wredf_(float v){
  #pragma unroll
  for (int o=32;o>0;o>>=1) v += __shfl_down(v, o);
  return v;
}

// ---------------------------------------------------------------------------
// MEGA PASS v6 = R16 work split over 512-thread blocks.
// R16 diagnosis: 4 blocks/CU x 4 waves = 16 waves/CU peak (Occ 29.6% avg),
// latency-bound. Same grid (1024) and same 2048 pos/block, but 512 threads
// x 1 batch -> 32 waves/CU resident. Histogram: 4 LDS copies (tid&3) to
// halve same-bin atomic chains. Everything else identical to R16.
// segacc: [0]=bce1 [1]=bce2 [2..9]=i1 [10..17]=x1 [18..25]=t1
//         [26..33]=i2 [34..41]=x2 [42..49]=t2
// ---------------------------------------------------------------------------
__global__ __launch_bounds__(512, 8) void k_mega(
  const float* __restrict__ us, const float* __restrict__ inputs,
  const float* __restrict__ train_mask, const float* __restrict__ tr_mask,
  const float* __restrict__ label,
  unsigned* __restrict__ ghc, float* __restrict__ ghs,
  float* __restrict__ pos_cf, float* __restrict__ pos_s,
  float* __restrict__ segacc)
{
  __shared__ unsigned s_cnt[4*4*NBIN];   // [copy(4)][ch][bin], 16KB
  __shared__ float    s_sum[4*4*NBIN];   // 16KB
  int tid = threadIdx.x;
  for (int j=tid;j<4*4*NBIN;j+=512){ s_cnt[j]=0u; s_sum[j]=0.f; }
  __syncthreads();

  int img = blockIdx.x>>7, chunk = blockIdx.x&127;
  int cpy = (tid&3)*4*NBIN;

  int p0 = chunk*2048 + tid*4;                 // coalesced: lane-stride 16B
  size_t gp = (size_t)img*NPIX + p0;

  // ---- 12 independent dwordx4 loads ----
  float4 tm4 = *(const float4*)(train_mask + gp);
  float4 lb4 = *(const float4*)(label + gp);
  const float4* t16 = (const float4*)(tr_mask + gp*4);
  float4 tv0 = t16[0], tv1 = t16[1], tv2 = t16[2], tv3 = t16[3];
  float4 xc0 = *(const float4*)(inputs + ((size_t)(img*4+0))*NPIX + p0);
  float4 xc1 = *(const float4*)(inputs + ((size_t)(img*4+1))*NPIX + p0);
  float4 xc2 = *(const float4*)(inputs + ((size_t)(img*4+2))*NPIX + p0);
  float4 xc3 = *(const float4*)(inputs + ((size_t)(img*4+3))*NPIX + p0);
  float4 ua4 = *(const float4*)(us + ((size_t)img*2  )*NPIX + p0);
  float4 ub4 = *(const float4*)(us + ((size_t)img*2+1)*NPIX + p0);

  float tm[4] = {tm4.x,tm4.y,tm4.z,tm4.w};
  float lb[4] = {lb4.x,lb4.y,lb4.z,lb4.w};
  float ta_[16] = {tv0.x,tv0.y,tv0.z,tv0.w, tv1.x,tv1.y,tv1.z,tv1.w,
                   tv2.x,tv2.y,tv2.z,tv2.w, tv3.x,tv3.y,tv3.z,tv3.w};
  float xs_[16] = {xc0.x,xc0.y,xc0.z,xc0.w, xc1.x,xc1.y,xc1.z,xc1.w,
                   xc2.x,xc2.y,xc2.z,xc2.w, xc3.x,xc3.y,xc3.z,xc3.w};

  float pcf[4]={0,0,0,0}, ps[4]={0,0,0,0};
  unsigned zc[4]={0,0,0,0};
  float bce1=0.f, i1=0.f, x1s=0.f, t1s=0.f;
  float bce2=0.f, i2=0.f, x2s=0.f, t2s=0.f;

  #pragma unroll
  for (int ch=0; ch<4; ++ch){
    #pragma unroll
    for (int j=0;j<4;++j){
      float t = ta_[j*4+ch];
      float x = xs_[ch*4+j];
      float E = __expf(-fabsf(x));               // native v_exp
      float r = __builtin_amdgcn_rcpf(1.f+E);    // sigmoid(|x|)
      float s = (x>=0.f)? r : 1.f-r;             // sigmoid(x)
      float d = s - t;
      float v = d*d*tm[j];                       // pre_loss in [0,1)
      if (t >= 0.001f){ pcf[ch]+=1.f; ps[ch]+=v; }
      else {
        unsigned code = rtne16_(v);              // <= 0x3F80
        if (code == 0u) zc[ch]++;                // zero-class: registers
        else {
          int b = cpy + ch*NBIN + (int)(code>>6);
          atomicAdd(&s_cnt[b], 1u);              // u32 atomics (R15 lesson)
          atomicAdd(&s_sum[b], v);
        }
      }
      if (ch==3){                                // seg2: last ch vs label
        float tt = lb[j];
        bce2 += fmaxf(x,0.f) - x*tt + __logf(1.f+E);
        i2 += s*tt; x2s += s; t2s += tt;
      }
    }
  }

  { // seg1: us channels vs one-hot(label)
    float aa[4]={ua4.x,ua4.y,ua4.z,ua4.w};
    float bb[4]={ub4.x,ub4.y,ub4.z,ub4.w};
    #pragma unroll
    for (int j=0;j<4;++j){
      float t1 = lb[j], t0 = 1.f - t1;
      float x0=aa[j], x1=bb[j];
      float E0 = __expf(-fabsf(x0)), E1 = __expf(-fabsf(x1));
      float r0 = __builtin_amdgcn_rcpf(1.f+E0);
      float r1 = __builtin_amdgcn_rcpf(1.f+E1);
      float s0 = (x0>=0.f)? r0 : 1.f-r0;
      float s1 = (x1>=0.f)? r1 : 1.f-r1;
      bce1 += fmaxf(x0,0.f) - x0*t0 + __logf(1.f+E0);
      bce1 += fmaxf(x1,0.f) - x1*t1 + __logf(1.f+E1);
      i1 += s0*t0 + s1*t1; x1s += s0+s1; t1s += t0+t1;
    }
  }

  #pragma unroll
  for (int ch=0;ch<4;++ch)
    if (zc[ch]) atomicAdd(&s_cnt[cpy + ch*NBIN], zc[ch]);   // bin0: count only

  // 16-scalar block reduction (8 waves)
  __shared__ float s_red[8][16];
  float red[16] = {pcf[0],pcf[1],pcf[2],pcf[3], ps[0],ps[1],ps[2],ps[3],
                   bce1, i1, x1s, t1s, bce2, i2, x2s, t2s};
  int wid = tid>>6, lane = tid&63;
  #pragma unroll
  for (int q=0;q<16;++q){
    float r = wredf_(red[q]);
    if (lane==0) s_red[wid][q] = r;
  }
  __syncthreads();
  if (tid < 16){
    float tot = 0.f;
    #pragma unroll
    for (int w2=0;w2<8;++w2) tot += s_red[w2][tid];
    int q = tid;
    if      (q<4)   atomicAdd(&pos_cf[img*4+q], tot);
    else if (q<8)   atomicAdd(&pos_s[img*4+q-4], tot);
    else if (q==8)  atomicAdd(&segacc[0], tot);
    else if (q==9)  atomicAdd(&segacc[2+img], tot);
    else if (q==10) atomicAdd(&segacc[10+img], tot);
    else if (q==11) atomicAdd(&segacc[18+img], tot);
    else if (q==12) atomicAdd(&segacc[1], tot);
    else if (q==13) atomicAdd(&segacc[26+img], tot);
    else if (q==14) atomicAdd(&segacc[34+img], tot);
    else            atomicAdd(&segacc[42+img], tot);
  }

  // flush merged histogram partials (<=2048 atomics/block, 128-deep chains)
  for (int j=tid;j<4*NBIN;j+=512){
    unsigned c = s_cnt[j] + s_cnt[1024+j] + s_cnt[2048+j] + s_cnt[3072+j];
    float    s = s_sum[j] + s_sum[1024+j] + s_sum[2048+j] + s_sum[3072+j];
    int ch = j>>8, bin = j&255;
    if (c)      atomicAdd(&ghc[(img*4+ch)*NBIN + bin], c);
    if (s!=0.f) atomicAdd(&ghs[(img*4+ch)*NBIN + bin], s);
  }
}

// ---------------------------------------------------------------------------
// POST: items + scalar fused in ONE single-block launch (1024 threads).
// Each row owned by a 32-lane group (lane t: bins [t*8, t*8+8)); shfl-based
// suffix scan (width 32); owner lane applies the order-statistics boundary
// correction (R14/R16: absmax 0.0). Then wave 0 assembles the scalar.
// Output: (h<<16)|h dual f32/bf16 encoding (proven).
// ---------------------------------------------------------------------------
__global__ __launch_bounds__(1024) void k_post(
  const unsigned* __restrict__ ghc, const float* __restrict__ ghs,
  const float* __restrict__ pos_cf, const float* __restrict__ pos_s,
  const float* __restrict__ segacc, const float* __restrict__ swp,
  unsigned* __restrict__ out)
{
  __shared__ float s_items[NROWS];
  int tid = threadIdx.x;
  int row = tid >> 5, t32 = tid & 31;

  {
    unsigned pc = (unsigned)pos_cf[row];
    float psv = pos_s[row];
    unsigned neg = (unsigned)NPIX - pc, k3 = 3u*pc;
    unsigned k = pc ? (neg<k3?neg:k3) : 100u;   // pos==0 -> top-100 fallback

    // per-lane bin segment
    unsigned bc[8]; float bsum=0.f; unsigned bcnt=0u;
    #pragma unroll
    for (int j=0;j<8;++j){
      int b = row*NBIN + t32*8 + j;
      bc[j] = ghc[b];
      bcnt += bc[j];
      bsum += ghs[b];
    }
    // inclusive SUFFIX scan across the 32-lane group
    unsigned suf_c = bcnt; float suf_s = bsum;
    #pragma unroll
    for (int o=1;o<32;o<<=1){
      unsigned c2 = __shfl_down(suf_c, o, 32);
      float    s2 = __shfl_down(suf_s, o, 32);
      if (t32 + o < 32){ suf_c += c2; suf_s += s2; }
    }
    unsigned nxt_c = __shfl_down(suf_c, 1, 32);
    float    nxt_s = __shfl_down(suf_s, 1, 32);
    if (t32 == 31){ nxt_c = 0u; nxt_s = 0.f; }

    if (k == 0u){
      if (t32==0) s_items[row] = psv/(float)(pc?pc:1u);
    } else if (t32==0 && suf_c < k){
      // cut in zero-class tail: top-k sum = all nonzero negs
      float ssel = suf_s;
      s_items[row] = pc ? (psv/(float)pc + ssel/(float)k) : (ssel/100.f);
    } else if (nxt_c < k && suf_c >= k){        // owner lane
      unsigned cnt = nxt_c; float sum = nxt_s;
      int bin = -1; unsigned c0 = 1u; float sown = 0.f;
      for (int j=7;j>=0;--j){
        unsigned c = bc[j];
        if (!c) continue;
        if (cnt + c >= k){ bin = t32*8 + j; c0 = c;
                           sown = ghs[row*NBIN + bin]; break; }
        cnt += c; sum += ghs[row*NBIN + t32*8 + j];
      }
      unsigned rem = k - cnt;                   // 1 <= rem <= c0
      float mean = sown / (float)c0;
      float lo = __uint_as_float(((unsigned)bin<<6)<<16);
      float hi = __uint_as_float((((unsigned)bin+1u)<<6)<<16);
      float wdt = hi - lo;
      float mtop = mean + 0.5f*wdt*(1.f - (float)rem/(float)c0);
      mtop = fminf(fmaxf(mtop, lo), hi);        // safety clamp
      float ssel = sum + (float)rem * mtop;
      s_items[row] = pc ? (psv/(float)pc + ssel/(float)k) : (ssel/100.f);
    }
  }
  __syncthreads();
  if (tid >= 64) return;

  // ---- scalar assembly on wave 0 ----
  float v = (tid<NROWS)? s_items[tid] : 0.f;
  v = wredf_(v);                                 // lane 0 gets total
  if (tid != 0) return;

  double lsum = (double)v;
  double sw = (double)swp[0];
  double loss = (lsum/8.0)/(2.0*sw*sw + 1e-6) - log(sw);
  double d1=0.0, d2=0.0;
  for (int i=0;i<8;++i){
    d1 += (2.0*(double)segacc[2+i]  + 1e-5)/((double)segacc[10+i] + (double)segacc[18+i] + 1e-5);
    d2 += (2.0*(double)segacc[26+i] + 1e-5)/((double)segacc[34+i] + (double)segacc[42+i] + 1e-5);
  }
  double seg1 = 0.5*((double)segacc[0]/(2.0*8.0*(double)NPIX)) + (1.0 - d1/8.0);
  double seg2 = 0.5*((double)segacc[1]/(8.0*(double)NPIX))     + (1.0 - d2/8.0);
  float tot = (float)(seg1 + seg2 + loss);
  unsigned u = __float_as_uint(tot);
  unsigned h = (u + 0x7FFFu + ((u>>16)&1u)) >> 16;   // RTNE bf16 bits
  out[0] = (h<<16) | h;                               // dual f32/bf16 encoding
}

// ---------------------------------------------------------------------------
extern "C" void kernel_launch(void* const* d_in, const int* in_sizes, int n_in,
                              void* d_out, int out_size, void* d_ws, size_t ws_size,
                              hipStream_t stream)
{
  const float* us         = (const float*)d_in[0];  // (8,2,512,512)
  const float* inputs     = (const float*)d_in[1];  // (8,4,512,512)
  const float* train_mask = (const float*)d_in[2];  // (8,1,512,512)
  const float* tr_mask    = (const float*)d_in[3];  // (8,512,512,4)
  const float* label      = (const float*)d_in[4];  // (8,1,512,512)
  const float* sw         = (const float*)d_in[5];  // (1,)

  char* w = (char*)d_ws;
  size_t off = 0;
  unsigned* ghc   = (unsigned*)(w+off); off += (size_t)NROWS*NBIN*4;  // 32KB
  float*    ghs   = (float*)(w+off);    off += (size_t)NROWS*NBIN*4;  // 32KB
  float*    pos_cf= (float*)(w+off);    off += NROWS*4;
  float*    pos_s = (float*)(w+off);    off += NROWS*4;
  float*    segacc= (float*)(w+off);    off += 64*4;
  size_t zbytes = off;                               // ~66KB zeroed each call

  hipMemsetAsync(w, 0, zbytes, stream);

  k_mega <<<dim3(1024), dim3(512),  0, stream>>>(us, inputs, train_mask, tr_mask,
                                                 label, ghc, ghs,
                                                 pos_cf, pos_s, segacc);
  k_post <<<dim3(1),    dim3(1024), 0, stream>>>(ghc, ghs, pos_cf, pos_s,
                                                 segacc, sw, (unsigned*)d_out);
}

// Round 18
// 53.362 us; speedup vs baseline: 1.7228x; 1.1350x over previous
//
#include <hip/hip_runtime.h>

#define NPIX (512*512)   // 262144
#define NROWS 32         // 8 images x 4 channels
#define NBIN 256         // half-octave bins: code>>6 of (f32bits>>16); v<1 => bin<=254

// RTNE round of f32 to its top-16 bits. Monotone in v for v>=0.
__device__ inline unsigned rtne16_(float v){
  unsigned u = __float_as_uint(v);
  return (u + 0x7FFFu + ((u>>16)&1u)) >> 16;
}

__device__ inline float wredf_(float v){
  #pragma unroll
  for (int o=32;o>0;o>>=1) v += __shfl_down(v, o);
  return v;
}

// ---------------------------------------------------------------------------
// MEGA PASS v7 = R17 + single-packed-u32 histogram atomic + 8 lane-split
// LDS copies. R17 diagnosis: occupancy 2x gave only -7% => per-CU LDS pipe
// bound (2 atomics/elem, hot-bin same-address chains). Pack cnt|fx_sum into
// one u32: (1<<20) | round(v*1024). Per copy-bin <=1024 elems * fx<=1024 =
// 2^20 max sum (fits), count 12 bits. Copies split by tid&7 (intra-wave
// lanes) so hot-bin chains drop 16->8 per instruction.
// grid: 1024 blocks x 512 thr (R17 geometry, best measured).
// segacc: [0]=bce1 [1]=bce2 [2..9]=i1 [10..17]=x1 [18..25]=t1
//         [26..33]=i2 [34..41]=x2 [42..49]=t2
// ---------------------------------------------------------------------------
__global__ __launch_bounds__(512, 8) void k_mega(
  const float* __restrict__ us, const float* __restrict__ inputs,
  const float* __restrict__ train_mask, const float* __restrict__ tr_mask,
  const float* __restrict__ label,
  unsigned* __restrict__ ghc, float* __restrict__ ghs,
  float* __restrict__ pos_cf, float* __restrict__ pos_s,
  float* __restrict__ segacc)
{
  __shared__ unsigned s_hist[8*4*NBIN];   // [copy(8)][ch][bin] packed, 32KB
  int tid = threadIdx.x;
  for (int j=tid;j<8*4*NBIN;j+=512) s_hist[j]=0u;
  __syncthreads();

  int img = blockIdx.x>>7, chunk = blockIdx.x&127;
  int cpy = (tid&7)*4*NBIN;

  int p0 = chunk*2048 + tid*4;                 // coalesced: lane-stride 16B
  size_t gp = (size_t)img*NPIX + p0;

  // ---- 12 independent dwordx4 loads ----
  float4 tm4 = *(const float4*)(train_mask + gp);
  float4 lb4 = *(const float4*)(label + gp);
  const float4* t16 = (const float4*)(tr_mask + gp*4);
  float4 tv0 = t16[0], tv1 = t16[1], tv2 = t16[2], tv3 = t16[3];
  float4 xc0 = *(const float4*)(inputs + ((size_t)(img*4+0))*NPIX + p0);
  float4 xc1 = *(const float4*)(inputs + ((size_t)(img*4+1))*NPIX + p0);
  float4 xc2 = *(const float4*)(inputs + ((size_t)(img*4+2))*NPIX + p0);
  float4 xc3 = *(const float4*)(inputs + ((size_t)(img*4+3))*NPIX + p0);
  float4 ua4 = *(const float4*)(us + ((size_t)img*2  )*NPIX + p0);
  float4 ub4 = *(const float4*)(us + ((size_t)img*2+1)*NPIX + p0);

  float tm[4] = {tm4.x,tm4.y,tm4.z,tm4.w};
  float lb[4] = {lb4.x,lb4.y,lb4.z,lb4.w};
  float ta_[16] = {tv0.x,tv0.y,tv0.z,tv0.w, tv1.x,tv1.y,tv1.z,tv1.w,
                   tv2.x,tv2.y,tv2.z,tv2.w, tv3.x,tv3.y,tv3.z,tv3.w};
  float xs_[16] = {xc0.x,xc0.y,xc0.z,xc0.w, xc1.x,xc1.y,xc1.z,xc1.w,
                   xc2.x,xc2.y,xc2.z,xc2.w, xc3.x,xc3.y,xc3.z,xc3.w};

  float pcf[4]={0,0,0,0}, ps[4]={0,0,0,0};
  unsigned zc[4]={0,0,0,0};
  float bce1=0.f, i1=0.f, x1s=0.f, t1s=0.f;
  float bce2=0.f, i2=0.f, x2s=0.f, t2s=0.f;

  #pragma unroll
  for (int ch=0; ch<4; ++ch){
    #pragma unroll
    for (int j=0;j<4;++j){
      float t = ta_[j*4+ch];
      float x = xs_[ch*4+j];
      float E = __expf(-fabsf(x));               // native v_exp
      float r = __builtin_amdgcn_rcpf(1.f+E);    // sigmoid(|x|)
      float s = (x>=0.f)? r : 1.f-r;             // sigmoid(x)
      float d = s - t;
      float v = d*d*tm[j];                       // pre_loss in [0,1)
      if (t >= 0.001f){ pcf[ch]+=1.f; ps[ch]+=v; }
      else {
        unsigned code = rtne16_(v);              // <= 0x3F80
        if (code == 0u) zc[ch]++;                // zero-class: registers
        else {
          unsigned fx = (unsigned)(v*1024.f + 0.5f);       // <= 1024
          atomicAdd(&s_hist[cpy + ch*NBIN + (int)(code>>6)],
                    (1u<<20) | fx);              // ONE packed u32 atomic
        }
      }
      if (ch==3){                                // seg2: last ch vs label
        float tt = lb[j];
        bce2 += fmaxf(x,0.f) - x*tt + __logf(1.f+E);
        i2 += s*tt; x2s += s; t2s += tt;
      }
    }
  }

  { // seg1: us channels vs one-hot(label)
    float aa[4]={ua4.x,ua4.y,ua4.z,ua4.w};
    float bb[4]={ub4.x,ub4.y,ub4.z,ub4.w};
    #pragma unroll
    for (int j=0;j<4;++j){
      float t1 = lb[j], t0 = 1.f - t1;
      float x0=aa[j], x1=bb[j];
      float E0 = __expf(-fabsf(x0)), E1 = __expf(-fabsf(x1));
      float r0 = __builtin_amdgcn_rcpf(1.f+E0);
      float r1 = __builtin_amdgcn_rcpf(1.f+E1);
      float s0 = (x0>=0.f)? r0 : 1.f-r0;
      float s1 = (x1>=0.f)? r1 : 1.f-r1;
      bce1 += fmaxf(x0,0.f) - x0*t0 + __logf(1.f+E0);
      bce1 += fmaxf(x1,0.f) - x1*t1 + __logf(1.f+E1);
      i1 += s0*t0 + s1*t1; x1s += s0+s1; t1s += t0+t1;
    }
  }

  #pragma unroll
  for (int ch=0;ch<4;++ch)
    if (zc[ch]) atomicAdd(&s_hist[cpy + ch*NBIN], zc[ch]<<20); // bin0: cnt only

  // 16-scalar block reduction (8 waves)
  __shared__ float s_red[8][16];
  float red[16] = {pcf[0],pcf[1],pcf[2],pcf[3], ps[0],ps[1],ps[2],ps[3],
                   bce1, i1, x1s, t1s, bce2, i2, x2s, t2s};
  int wid = tid>>6, lane = tid&63;
  #pragma unroll
  for (int q=0;q<16;++q){
    float r = wredf_(red[q]);
    if (lane==0) s_red[wid][q] = r;
  }
  __syncthreads();
  if (tid < 16){
    float tot = 0.f;
    #pragma unroll
    for (int w2=0;w2<8;++w2) tot += s_red[w2][tid];
    int q = tid;
    if      (q<4)   atomicAdd(&pos_cf[img*4+q], tot);
    else if (q<8)   atomicAdd(&pos_s[img*4+q-4], tot);
    else if (q==8)  atomicAdd(&segacc[0], tot);
    else if (q==9)  atomicAdd(&segacc[2+img], tot);
    else if (q==10) atomicAdd(&segacc[10+img], tot);
    else if (q==11) atomicAdd(&segacc[18+img], tot);
    else if (q==12) atomicAdd(&segacc[1], tot);
    else if (q==13) atomicAdd(&segacc[26+img], tot);
    else if (q==14) atomicAdd(&segacc[34+img], tot);
    else            atomicAdd(&segacc[42+img], tot);
  }

  // flush: unpack 8 copies -> cnt + float sum; <=2048 global atomics/block
  for (int j=tid;j<4*NBIN;j+=512){
    unsigned c=0u, fsum=0u;
    #pragma unroll
    for (int cp=0;cp<8;++cp){
      unsigned p = s_hist[cp*1024 + j];
      c    += p>>20;
      fsum += p & 0xFFFFFu;
    }
    int ch = j>>8, bin = j&255;
    if (c){
      atomicAdd(&ghc[(img*4+ch)*NBIN + bin], c);
      float s = (float)fsum * (1.f/1024.f);
      if (s!=0.f) atomicAdd(&ghs[(img*4+ch)*NBIN + bin], s);
    }
  }
}

// ---------------------------------------------------------------------------
// POST: items + scalar fused in ONE single-block launch (1024 threads).
// Each row owned by a 32-lane group (lane t: bins [t*8, t*8+8)); shfl-based
// suffix scan (width 32); owner lane applies the order-statistics boundary
// correction (R14/R16/R17: absmax 0.0). Then wave 0 assembles the scalar.
// Output: (h<<16)|h dual f32/bf16 encoding (proven).
// ---------------------------------------------------------------------------
__global__ __launch_bounds__(1024) void k_post(
  const unsigned* __restrict__ ghc, const float* __restrict__ ghs,
  const float* __restrict__ pos_cf, const float* __restrict__ pos_s,
  const float* __restrict__ segacc, const float* __restrict__ swp,
  unsigned* __restrict__ out)
{
  __shared__ float s_items[NROWS];
  int tid = threadIdx.x;
  int row = tid >> 5, t32 = tid & 31;

  {
    unsigned pc = (unsigned)pos_cf[row];
    float psv = pos_s[row];
    unsigned neg = (unsigned)NPIX - pc, k3 = 3u*pc;
    unsigned k = pc ? (neg<k3?neg:k3) : 100u;   // pos==0 -> top-100 fallback

    unsigned bc[8]; float bsum=0.f; unsigned bcnt=0u;
    #pragma unroll
    for (int j=0;j<8;++j){
      int b = row*NBIN + t32*8 + j;
      bc[j] = ghc[b];
      bcnt += bc[j];
      bsum += ghs[b];
    }
    unsigned suf_c = bcnt; float suf_s = bsum;
    #pragma unroll
    for (int o=1;o<32;o<<=1){
      unsigned c2 = __shfl_down(suf_c, o, 32);
      float    s2 = __shfl_down(suf_s, o, 32);
      if (t32 + o < 32){ suf_c += c2; suf_s += s2; }
    }
    unsigned nxt_c = __shfl_down(suf_c, 1, 32);
    float    nxt_s = __shfl_down(suf_s, 1, 32);
    if (t32 == 31){ nxt_c = 0u; nxt_s = 0.f; }

    if (k == 0u){
      if (t32==0) s_items[row] = psv/(float)(pc?pc:1u);
    } else if (t32==0 && suf_c < k){
      float ssel = suf_s;                       // cut in zero-class tail
      s_items[row] = pc ? (psv/(float)pc + ssel/(float)k) : (ssel/100.f);
    } else if (nxt_c < k && suf_c >= k){        // owner lane
      unsigned cnt = nxt_c; float sum = nxt_s;
      int bin = -1; unsigned c0 = 1u; float sown = 0.f;
      for (int j=7;j>=0;--j){
        unsigned c = bc[j];
        if (!c) continue;
        if (cnt + c >= k){ bin = t32*8 + j; c0 = c;
                           sown = ghs[row*NBIN + bin]; break; }
        cnt += c; sum += ghs[row*NBIN + t32*8 + j];
      }
      unsigned rem = k - cnt;                   // 1 <= rem <= c0
      float mean = sown / (float)c0;
      float lo = __uint_as_float(((unsigned)bin<<6)<<16);
      float hi = __uint_as_float((((unsigned)bin+1u)<<6)<<16);
      float wdt = hi - lo;
      float mtop = mean + 0.5f*wdt*(1.f - (float)rem/(float)c0);
      mtop = fminf(fmaxf(mtop, lo), hi);        // safety clamp
      float ssel = sum + (float)rem * mtop;
      s_items[row] = pc ? (psv/(float)pc + ssel/(float)k) : (ssel/100.f);
    }
  }
  __syncthreads();
  if (tid >= 64) return;

  // ---- scalar assembly on wave 0 ----
  float v = (tid<NROWS)? s_items[tid] : 0.f;
  v = wredf_(v);                                 // lane 0 gets total
  if (tid != 0) return;

  double lsum = (double)v;
  double sw = (double)swp[0];
  double loss = (lsum/8.0)/(2.0*sw*sw + 1e-6) - log(sw);
  double d1=0.0, d2=0.0;
  for (int i=0;i<8;++i){
    d1 += (2.0*(double)segacc[2+i]  + 1e-5)/((double)segacc[10+i] + (double)segacc[18+i] + 1e-5);
    d2 += (2.0*(double)segacc[26+i] + 1e-5)/((double)segacc[34+i] + (double)segacc[42+i] + 1e-5);
  }
  double seg1 = 0.5*((double)segacc[0]/(2.0*8.0*(double)NPIX)) + (1.0 - d1/8.0);
  double seg2 = 0.5*((double)segacc[1]/(8.0*(double)NPIX))     + (1.0 - d2/8.0);
  float tot = (float)(seg1 + seg2 + loss);
  unsigned u = __float_as_uint(tot);
  unsigned h = (u + 0x7FFFu + ((u>>16)&1u)) >> 16;   // RTNE bf16 bits
  out[0] = (h<<16) | h;                               // dual f32/bf16 encoding
}

// ---------------------------------------------------------------------------
extern "C" void kernel_launch(void* const* d_in, const int* in_sizes, int n_in,
                              void* d_out, int out_size, void* d_ws, size_t ws_size,
                              hipStream_t stream)
{
  const float* us         = (const float*)d_in[0];  // (8,2,512,512)
  const float* inputs     = (const float*)d_in[1];  // (8,4,512,512)
  const float* train_mask = (const float*)d_in[2];  // (8,1,512,512)
  const float* tr_mask    = (const float*)d_in[3];  // (8,512,512,4)
  const float* label      = (const float*)d_in[4];  // (8,1,512,512)
  const float* sw         = (const float*)d_in[5];  // (1,)

  char* w = (char*)d_ws;
  size_t off = 0;
  unsigned* ghc   = (unsigned*)(w+off); off += (size_t)NROWS*NBIN*4;  // 32KB
  float*    ghs   = (float*)(w+off);    off += (size_t)NROWS*NBIN*4;  // 32KB
  float*    pos_cf= (float*)(w+off);    off += NROWS*4;
  float*    pos_s = (float*)(w+off);    off += NROWS*4;
  float*    segacc= (float*)(w+off);    off += 64*4;
  size_t zbytes = off;                               // ~66KB zeroed each call

  hipMemsetAsync(w, 0, zbytes, stream);

  k_mega <<<dim3(1024), dim3(512),  0, stream>>>(us, inputs, train_mask, tr_mask,
                                                 label, ghc, ghs,
                                                 pos_cf, pos_s, segacc);
  k_post <<<dim3(1),    dim3(1024), 0, stream>>>(ghc, ghs, pos_cf, pos_s,
                                                 segacc, sw, (unsigned*)d_out);
}

// Round 19
// 41.399 us; speedup vs baseline: 2.2206x; 1.2889x over previous
//
#include <hip/hip_runtime.h>

#define NPIX (512*512)   // 262144
#define NROWS 32         // 8 images x 4 channels
#define NBIN 256         // half-octave bins: code>>6 of (f32bits>>16); v<1 => bin<=254

// RTNE round of f32 to its top-16 bits. Monotone in v for v>=0.
__device__ inline unsigned rtne16_(float v){
  unsigned u = __float_as_uint(v);
  return (u + 0x7FFFu + ((u>>16)&1u)) >> 16;
}

__device__ inline float wredf_(float v){
  #pragma unroll
  for (int o=32;o>0;o>>=1) v += __shfl_down(v, o);
  return v;
}

// ---------------------------------------------------------------------------
// MEGA PASS v8 = R18 math + 1024-thread blocks + 16 LDS histogram copies.
// R18 diagnosis: LDS-pipe + phase-lockstep bound (occupancy 50%, warm replay
// == cold). 16 copies -> same-address chain 8->4 lanes/copy; 2 blocks x 16
// waves = 32 waves/CU (full cap); flush in ONE pass (1024 lanes x 1024 bins).
// Pack: (1<<21)|fx, fx=round(v*1024): per copy <=1024 elems * fx<=1024 =
// 2^20 < 2^21 -- provably no overflow into the count field (bits 21..31).
// grid: 8 img x 64 chunks = 512 blocks x 1024 thr; 4 consecutive pos/thread.
// segacc: [0]=bce1 [1]=bce2 [2..9]=i1 [10..17]=x1 [18..25]=t1
//         [26..33]=i2 [34..41]=x2 [42..49]=t2
// ---------------------------------------------------------------------------
__global__ __launch_bounds__(1024, 2) void k_mega(
  const float* __restrict__ us, const float* __restrict__ inputs,
  const float* __restrict__ train_mask, const float* __restrict__ tr_mask,
  const float* __restrict__ label,
  unsigned* __restrict__ ghc, float* __restrict__ ghs,
  float* __restrict__ pos_cf, float* __restrict__ pos_s,
  float* __restrict__ segacc)
{
  __shared__ unsigned s_hist[16*4*NBIN];  // [copy(16)][ch][bin] packed, 64KB
  int tid = threadIdx.x;
  #pragma unroll
  for (int j=0;j<16;++j) s_hist[j*1024 + tid] = 0u;
  __syncthreads();

  int img = blockIdx.x>>6, chunk = blockIdx.x&63;
  int cpy = (tid&15)*1024;

  int p0 = chunk*4096 + tid*4;                 // coalesced: lane-stride 16B
  size_t gp = (size_t)img*NPIX + p0;

  // ---- 12 independent dwordx4 loads ----
  float4 tm4 = *(const float4*)(train_mask + gp);
  float4 lb4 = *(const float4*)(label + gp);
  const float4* t16 = (const float4*)(tr_mask + gp*4);
  float4 tv0 = t16[0], tv1 = t16[1], tv2 = t16[2], tv3 = t16[3];
  float4 xc0 = *(const float4*)(inputs + ((size_t)(img*4+0))*NPIX + p0);
  float4 xc1 = *(const float4*)(inputs + ((size_t)(img*4+1))*NPIX + p0);
  float4 xc2 = *(const float4*)(inputs + ((size_t)(img*4+2))*NPIX + p0);
  float4 xc3 = *(const float4*)(inputs + ((size_t)(img*4+3))*NPIX + p0);
  float4 ua4 = *(const float4*)(us + ((size_t)img*2  )*NPIX + p0);
  float4 ub4 = *(const float4*)(us + ((size_t)img*2+1)*NPIX + p0);

  float tm[4] = {tm4.x,tm4.y,tm4.z,tm4.w};
  float lb[4] = {lb4.x,lb4.y,lb4.z,lb4.w};
  float ta_[16] = {tv0.x,tv0.y,tv0.z,tv0.w, tv1.x,tv1.y,tv1.z,tv1.w,
                   tv2.x,tv2.y,tv2.z,tv2.w, tv3.x,tv3.y,tv3.z,tv3.w};
  float xs_[16] = {xc0.x,xc0.y,xc0.z,xc0.w, xc1.x,xc1.y,xc1.z,xc1.w,
                   xc2.x,xc2.y,xc2.z,xc2.w, xc3.x,xc3.y,xc3.z,xc3.w};

  float pcf[4]={0,0,0,0}, ps[4]={0,0,0,0};
  unsigned zc[4]={0,0,0,0};
  float bce1=0.f, i1=0.f, x1s=0.f, t1s=0.f;
  float bce2=0.f, i2=0.f, x2s=0.f, t2s=0.f;

  #pragma unroll
  for (int ch=0; ch<4; ++ch){
    #pragma unroll
    for (int j=0;j<4;++j){
      float t = ta_[j*4+ch];
      float x = xs_[ch*4+j];
      float E = __expf(-fabsf(x));               // native v_exp
      float r = __builtin_amdgcn_rcpf(1.f+E);    // sigmoid(|x|)
      float s = (x>=0.f)? r : 1.f-r;             // sigmoid(x)
      float d = s - t;
      float v = d*d*tm[j];                       // pre_loss in [0,1)
      if (t >= 0.001f){ pcf[ch]+=1.f; ps[ch]+=v; }
      else {
        unsigned code = rtne16_(v);              // <= 0x3F80
        if (code == 0u) zc[ch]++;                // zero-class: registers
        else {
          unsigned fx = (unsigned)(v*1024.f + 0.5f);       // <= 1024
          atomicAdd(&s_hist[cpy + ch*NBIN + (int)(code>>6)],
                    (1u<<21) | fx);              // ONE packed u32 atomic
        }
      }
      if (ch==3){                                // seg2: last ch vs label
        float tt = lb[j];
        bce2 += fmaxf(x,0.f) - x*tt + __logf(1.f+E);
        i2 += s*tt; x2s += s; t2s += tt;
      }
    }
  }

  { // seg1: us channels vs one-hot(label)
    float aa[4]={ua4.x,ua4.y,ua4.z,ua4.w};
    float bb[4]={ub4.x,ub4.y,ub4.z,ub4.w};
    #pragma unroll
    for (int j=0;j<4;++j){
      float t1 = lb[j], t0 = 1.f - t1;
      float x0=aa[j], x1=bb[j];
      float E0 = __expf(-fabsf(x0)), E1 = __expf(-fabsf(x1));
      float r0 = __builtin_amdgcn_rcpf(1.f+E0);
      float r1 = __builtin_amdgcn_rcpf(1.f+E1);
      float s0 = (x0>=0.f)? r0 : 1.f-r0;
      float s1 = (x1>=0.f)? r1 : 1.f-r1;
      bce1 += fmaxf(x0,0.f) - x0*t0 + __logf(1.f+E0);
      bce1 += fmaxf(x1,0.f) - x1*t1 + __logf(1.f+E1);
      i1 += s0*t0 + s1*t1; x1s += s0+s1; t1s += t0+t1;
    }
  }

  #pragma unroll
  for (int ch=0;ch<4;++ch)
    if (zc[ch]) atomicAdd(&s_hist[cpy + ch*NBIN], zc[ch]<<21); // bin0: cnt only

  // 16-scalar block reduction (16 waves)
  __shared__ float s_red[16][16];
  float red[16] = {pcf[0],pcf[1],pcf[2],pcf[3], ps[0],ps[1],ps[2],ps[3],
                   bce1, i1, x1s, t1s, bce2, i2, x2s, t2s};
  int wid = tid>>6, lane = tid&63;
  #pragma unroll
  for (int q=0;q<16;++q){
    float r = wredf_(red[q]);
    if (lane==0) s_red[wid][q] = r;
  }
  __syncthreads();
  if (tid < 16){
    float tot = 0.f;
    #pragma unroll
    for (int w2=0;w2<16;++w2) tot += s_red[w2][tid];
    int q = tid;
    if      (q<4)   atomicAdd(&pos_cf[img*4+q], tot);
    else if (q<8)   atomicAdd(&pos_s[img*4+q-4], tot);
    else if (q==8)  atomicAdd(&segacc[0], tot);
    else if (q==9)  atomicAdd(&segacc[2+img], tot);
    else if (q==10) atomicAdd(&segacc[10+img], tot);
    else if (q==11) atomicAdd(&segacc[18+img], tot);
    else if (q==12) atomicAdd(&segacc[1], tot);
    else if (q==13) atomicAdd(&segacc[26+img], tot);
    else if (q==14) atomicAdd(&segacc[34+img], tot);
    else            atomicAdd(&segacc[42+img], tot);
  }

  // flush: ONE pass (1024 lanes x 1024 bins), unpack 16 copies
  {
    int j = tid;                                 // 0..1023 = [ch][bin]
    unsigned c=0u, fsum=0u;
    #pragma unroll
    for (int cp=0;cp<16;++cp){
      unsigned p = s_hist[cp*1024 + j];
      c    += p>>21;
      fsum += p & 0x1FFFFFu;
    }
    int ch = j>>8, bin = j&255;
    if (c){
      atomicAdd(&ghc[(img*4+ch)*NBIN + bin], c);
      float s = (float)fsum * (1.f/1024.f);
      if (s!=0.f) atomicAdd(&ghs[(img*4+ch)*NBIN + bin], s);
    }
  }
}

// ---------------------------------------------------------------------------
// POST: items + scalar fused in ONE single-block launch (1024 threads).
// Each row owned by a 32-lane group (lane t: bins [t*8, t*8+8)); shfl-based
// suffix scan (width 32); owner lane applies the order-statistics boundary
// correction (R14/R16/R17/R18: absmax 0.0). Then wave 0 assembles the scalar.
// Output: (h<<16)|h dual f32/bf16 encoding (proven).
// ---------------------------------------------------------------------------
__global__ __launch_bounds__(1024) void k_post(
  const unsigned* __restrict__ ghc, const float* __restrict__ ghs,
  const float* __restrict__ pos_cf, const float* __restrict__ pos_s,
  const float* __restrict__ segacc, const float* __restrict__ swp,
  unsigned* __restrict__ out)
{
  __shared__ float s_items[NROWS];
  int tid = threadIdx.x;
  int row = tid >> 5, t32 = tid & 31;

  {
    unsigned pc = (unsigned)pos_cf[row];
    float psv = pos_s[row];
    unsigned neg = (unsigned)NPIX - pc, k3 = 3u*pc;
    unsigned k = pc ? (neg<k3?neg:k3) : 100u;   // pos==0 -> top-100 fallback

    unsigned bc[8]; float bsum=0.f; unsigned bcnt=0u;
    #pragma unroll
    for (int j=0;j<8;++j){
      int b = row*NBIN + t32*8 + j;
      bc[j] = ghc[b];
      bcnt += bc[j];
      bsum += ghs[b];
    }
    unsigned suf_c = bcnt; float suf_s = bsum;
    #pragma unroll
    for (int o=1;o<32;o<<=1){
      unsigned c2 = __shfl_down(suf_c, o, 32);
      float    s2 = __shfl_down(suf_s, o, 32);
      if (t32 + o < 32){ suf_c += c2; suf_s += s2; }
    }
    unsigned nxt_c = __shfl_down(suf_c, 1, 32);
    float    nxt_s = __shfl_down(suf_s, 1, 32);
    if (t32 == 31){ nxt_c = 0u; nxt_s = 0.f; }

    if (k == 0u){
      if (t32==0) s_items[row] = psv/(float)(pc?pc:1u);
    } else if (t32==0 && suf_c < k){
      float ssel = suf_s;                       // cut in zero-class tail
      s_items[row] = pc ? (psv/(float)pc + ssel/(float)k) : (ssel/100.f);
    } else if (nxt_c < k && suf_c >= k){        // owner lane
      unsigned cnt = nxt_c; float sum = nxt_s;
      int bin = -1; unsigned c0 = 1u; float sown = 0.f;
      for (int j=7;j>=0;--j){
        unsigned c = bc[j];
        if (!c) continue;
        if (cnt + c >= k){ bin = t32*8 + j; c0 = c;
                           sown = ghs[row*NBIN + bin]; break; }
        cnt += c; sum += ghs[row*NBIN + t32*8 + j];
      }
      unsigned rem = k - cnt;                   // 1 <= rem <= c0
      float mean = sown / (float)c0;
      float lo = __uint_as_float(((unsigned)bin<<6)<<16);
      float hi = __uint_as_float((((unsigned)bin+1u)<<6)<<16);
      float wdt = hi - lo;
      float mtop = mean + 0.5f*wdt*(1.f - (float)rem/(float)c0);
      mtop = fminf(fmaxf(mtop, lo), hi);        // safety clamp
      float ssel = sum + (float)rem * mtop;
      s_items[row] = pc ? (psv/(float)pc + ssel/(float)k) : (ssel/100.f);
    }
  }
  __syncthreads();
  if (tid >= 64) return;

  // ---- scalar assembly on wave 0 ----
  float v = (tid<NROWS)? s_items[tid] : 0.f;
  v = wredf_(v);                                 // lane 0 gets total
  if (tid != 0) return;

  double lsum = (double)v;
  double sw = (double)swp[0];
  double loss = (lsum/8.0)/(2.0*sw*sw + 1e-6) - log(sw);
  double d1=0.0, d2=0.0;
  for (int i=0;i<8;++i){
    d1 += (2.0*(double)segacc[2+i]  + 1e-5)/((double)segacc[10+i] + (double)segacc[18+i] + 1e-5);
    d2 += (2.0*(double)segacc[26+i] + 1e-5)/((double)segacc[34+i] + (double)segacc[42+i] + 1e-5);
  }
  double seg1 = 0.5*((double)segacc[0]/(2.0*8.0*(double)NPIX)) + (1.0 - d1/8.0);
  double seg2 = 0.5*((double)segacc[1]/(8.0*(double)NPIX))     + (1.0 - d2/8.0);
  float tot = (float)(seg1 + seg2 + loss);
  unsigned u = __float_as_uint(tot);
  unsigned h = (u + 0x7FFFu + ((u>>16)&1u)) >> 16;   // RTNE bf16 bits
  out[0] = (h<<16) | h;                               // dual f32/bf16 encoding
}

// ---------------------------------------------------------------------------
extern "C" void kernel_launch(void* const* d_in, const int* in_sizes, int n_in,
                              void* d_out, int out_size, void* d_ws, size_t ws_size,
                              hipStream_t stream)
{
  const float* us         = (const float*)d_in[0];  // (8,2,512,512)
  const float* inputs     = (const float*)d_in[1];  // (8,4,512,512)
  const float* train_mask = (const float*)d_in[2];  // (8,1,512,512)
  const float* tr_mask    = (const float*)d_in[3];  // (8,512,512,4)
  const float* label      = (const float*)d_in[4];  // (8,1,512,512)
  const float* sw         = (const float*)d_in[5];  // (1,)

  char* w = (char*)d_ws;
  size_t off = 0;
  unsigned* ghc   = (unsigned*)(w+off); off += (size_t)NROWS*NBIN*4;  // 32KB
  float*    ghs   = (float*)(w+off);    off += (size_t)NROWS*NBIN*4;  // 32KB
  float*    pos_cf= (float*)(w+off);    off += NROWS*4;
  float*    pos_s = (float*)(w+off);    off += NROWS*4;
  float*    segacc= (float*)(w+off);    off += 64*4;
  size_t zbytes = off;                               // ~66KB zeroed each call

  hipMemsetAsync(w, 0, zbytes, stream);

  k_mega <<<dim3(512),  dim3(1024), 0, stream>>>(us, inputs, train_mask, tr_mask,
                                                 label, ghc, ghs,
                                                 pos_cf, pos_s, segacc);
  k_post <<<dim3(1),    dim3(1024), 0, stream>>>(ghc, ghs, pos_cf, pos_s,
                                                 segacc, sw, (unsigned*)d_out);
}

// Round 20
// 40.021 us; speedup vs baseline: 2.2971x; 1.0344x over previous
//
#include <hip/hip_runtime.h>

#define NPIX (512*512)   // 262144
#define NROWS 32         // 8 images x 4 channels
#define NBIN 256         // half-octave bins: code>>6 of (f32bits>>16); v<1 => bin<=254
#define HSTR 1026        // copy stride in words: 1026 % 32 = 2 -> 16 copies hit
                         // 16 DISTINCT banks for the same bin (R19 used 1024,
                         // which put ALL copies of a bin in ONE bank)

// RTNE round of f32 to its top-16 bits. Monotone in v for v>=0.
__device__ inline unsigned rtne16_(float v){
  unsigned u = __float_as_uint(v);
  return (u + 0x7FFFu + ((u>>16)&1u)) >> 16;
}

__device__ inline float wredf_(float v){
  #pragma unroll
  for (int o=32;o>0;o>>=1) v += __shfl_down(v, o);
  return v;
}

// ---------------------------------------------------------------------------
// MEGA PASS v9 = R19 + bank-padded copy stride.
// R19 bank arithmetic: stride 1024 = 0 mod 32 -> all 16 copies of a hot bin
// in ONE bank -> up to 64-way serialization per instruction despite copies.
// Stride 1026 spreads the 16 copies over 16 distinct banks; worst case is
// the 4-way same-address chain within a copy (free-ish per G4).
// grid: 8 img x 64 chunks = 512 blocks x 1024 thr; 4 consecutive pos/thread.
// Pack: (1<<21)|fx, fx=round(v*1024): per copy <=1024 elems * fx<=1024 =
// 2^20 < 2^21 -- no overflow into the count field.
// segacc: [0]=bce1 [1]=bce2 [2..9]=i1 [10..17]=x1 [18..25]=t1
//         [26..33]=i2 [34..41]=x2 [42..49]=t2
// ---------------------------------------------------------------------------
__global__ __launch_bounds__(1024, 2) void k_mega(
  const float* __restrict__ us, const float* __restrict__ inputs,
  const float* __restrict__ train_mask, const float* __restrict__ tr_mask,
  const float* __restrict__ label,
  unsigned* __restrict__ ghc, float* __restrict__ ghs,
  float* __restrict__ pos_cf, float* __restrict__ pos_s,
  float* __restrict__ segacc)
{
  __shared__ unsigned s_hist[16*HSTR];    // [copy(16)][ch][bin] packed, 65.7KB
  int tid = threadIdx.x;
  for (int j=tid;j<16*HSTR;j+=1024) s_hist[j]=0u;
  __syncthreads();

  int img = blockIdx.x>>6, chunk = blockIdx.x&63;
  int cpy = (tid&15)*HSTR;

  int p0 = chunk*4096 + tid*4;                 // coalesced: lane-stride 16B
  size_t gp = (size_t)img*NPIX + p0;

  // ---- 12 independent dwordx4 loads ----
  float4 tm4 = *(const float4*)(train_mask + gp);
  float4 lb4 = *(const float4*)(label + gp);
  const float4* t16 = (const float4*)(tr_mask + gp*4);
  float4 tv0 = t16[0], tv1 = t16[1], tv2 = t16[2], tv3 = t16[3];
  float4 xc0 = *(const float4*)(inputs + ((size_t)(img*4+0))*NPIX + p0);
  float4 xc1 = *(const float4*)(inputs + ((size_t)(img*4+1))*NPIX + p0);
  float4 xc2 = *(const float4*)(inputs + ((size_t)(img*4+2))*NPIX + p0);
  float4 xc3 = *(const float4*)(inputs + ((size_t)(img*4+3))*NPIX + p0);
  float4 ua4 = *(const float4*)(us + ((size_t)img*2  )*NPIX + p0);
  float4 ub4 = *(const float4*)(us + ((size_t)img*2+1)*NPIX + p0);

  float tm[4] = {tm4.x,tm4.y,tm4.z,tm4.w};
  float lb[4] = {lb4.x,lb4.y,lb4.z,lb4.w};
  float ta_[16] = {tv0.x,tv0.y,tv0.z,tv0.w, tv1.x,tv1.y,tv1.z,tv1.w,
                   tv2.x,tv2.y,tv2.z,tv2.w, tv3.x,tv3.y,tv3.z,tv3.w};
  float xs_[16] = {xc0.x,xc0.y,xc0.z,xc0.w, xc1.x,xc1.y,xc1.z,xc1.w,
                   xc2.x,xc2.y,xc2.z,xc2.w, xc3.x,xc3.y,xc3.z,xc3.w};

  float pcf[4]={0,0,0,0}, ps[4]={0,0,0,0};
  unsigned zc[4]={0,0,0,0};
  float bce1=0.f, i1=0.f, x1s=0.f, t1s=0.f;
  float bce2=0.f, i2=0.f, x2s=0.f, t2s=0.f;

  #pragma unroll
  for (int ch=0; ch<4; ++ch){
    #pragma unroll
    for (int j=0;j<4;++j){
      float t = ta_[j*4+ch];
      float x = xs_[ch*4+j];
      float E = __expf(-fabsf(x));               // native v_exp
      float r = __builtin_amdgcn_rcpf(1.f+E);    // sigmoid(|x|)
      float s = (x>=0.f)? r : 1.f-r;             // sigmoid(x)
      float d = s - t;
      float v = d*d*tm[j];                       // pre_loss in [0,1)
      if (t >= 0.001f){ pcf[ch]+=1.f; ps[ch]+=v; }
      else {
        unsigned code = rtne16_(v);              // <= 0x3F80
        if (code == 0u) zc[ch]++;                // zero-class: registers
        else {
          unsigned fx = (unsigned)(v*1024.f + 0.5f);       // <= 1024
          atomicAdd(&s_hist[cpy + ch*NBIN + (int)(code>>6)],
                    (1u<<21) | fx);              // ONE packed u32 atomic
        }
      }
      if (ch==3){                                // seg2: last ch vs label
        float tt = lb[j];
        bce2 += fmaxf(x,0.f) - x*tt + __logf(1.f+E);
        i2 += s*tt; x2s += s; t2s += tt;
      }
    }
  }

  { // seg1: us channels vs one-hot(label)
    float aa[4]={ua4.x,ua4.y,ua4.z,ua4.w};
    float bb[4]={ub4.x,ub4.y,ub4.z,ub4.w};
    #pragma unroll
    for (int j=0;j<4;++j){
      float t1 = lb[j], t0 = 1.f - t1;
      float x0=aa[j], x1=bb[j];
      float E0 = __expf(-fabsf(x0)), E1 = __expf(-fabsf(x1));
      float r0 = __builtin_amdgcn_rcpf(1.f+E0);
      float r1 = __builtin_amdgcn_rcpf(1.f+E1);
      float s0 = (x0>=0.f)? r0 : 1.f-r0;
      float s1 = (x1>=0.f)? r1 : 1.f-r1;
      bce1 += fmaxf(x0,0.f) - x0*t0 + __logf(1.f+E0);
      bce1 += fmaxf(x1,0.f) - x1*t1 + __logf(1.f+E1);
      i1 += s0*t0 + s1*t1; x1s += s0+s1; t1s += t0+t1;
    }
  }

  #pragma unroll
  for (int ch=0;ch<4;++ch)
    if (zc[ch]) atomicAdd(&s_hist[cpy + ch*NBIN], zc[ch]<<21); // bin0: cnt only

  // 16-scalar block reduction (16 waves)
  __shared__ float s_red[16][16];
  float red[16] = {pcf[0],pcf[1],pcf[2],pcf[3], ps[0],ps[1],ps[2],ps[3],
                   bce1, i1, x1s, t1s, bce2, i2, x2s, t2s};
  int wid = tid>>6, lane = tid&63;
  #pragma unroll
  for (int q=0;q<16;++q){
    float r = wredf_(red[q]);
    if (lane==0) s_red[wid][q] = r;
  }
  __syncthreads();
  if (tid < 16){
    float tot = 0.f;
    #pragma unroll
    for (int w2=0;w2<16;++w2) tot += s_red[w2][tid];
    int q = tid;
    if      (q<4)   atomicAdd(&pos_cf[img*4+q], tot);
    else if (q<8)   atomicAdd(&pos_s[img*4+q-4], tot);
    else if (q==8)  atomicAdd(&segacc[0], tot);
    else if (q==9)  atomicAdd(&segacc[2+img], tot);
    else if (q==10) atomicAdd(&segacc[10+img], tot);
    else if (q==11) atomicAdd(&segacc[18+img], tot);
    else if (q==12) atomicAdd(&segacc[1], tot);
    else if (q==13) atomicAdd(&segacc[26+img], tot);
    else if (q==14) atomicAdd(&segacc[34+img], tot);
    else            atomicAdd(&segacc[42+img], tot);
  }

  // flush: ONE pass (1024 lanes x 1024 bins), unpack 16 copies
  {
    int j = tid;                                 // 0..1023 = [ch][bin]
    unsigned c=0u, fsum=0u;
    #pragma unroll
    for (int cp=0;cp<16;++cp){
      unsigned p = s_hist[cp*HSTR + j];
      c    += p>>21;
      fsum += p & 0x1FFFFFu;
    }
    int ch = j>>8, bin = j&255;
    if (c){
      atomicAdd(&ghc[(img*4+ch)*NBIN + bin], c);
      float s = (float)fsum * (1.f/1024.f);
      if (s!=0.f) atomicAdd(&ghs[(img*4+ch)*NBIN + bin], s);
    }
  }
}

// ---------------------------------------------------------------------------
// POST: items + scalar fused in ONE single-block launch (1024 threads).
// Each row owned by a 32-lane group (lane t: bins [t*8, t*8+8)); shfl-based
// suffix scan (width 32); owner lane applies the order-statistics boundary
// correction (R14..R19: absmax 0.0). Then wave 0 assembles the scalar.
// Output: (h<<16)|h dual f32/bf16 encoding (proven).
// ---------------------------------------------------------------------------
__global__ __launch_bounds__(1024) void k_post(
  const unsigned* __restrict__ ghc, const float* __restrict__ ghs,
  const float* __restrict__ pos_cf, const float* __restrict__ pos_s,
  const float* __restrict__ segacc, const float* __restrict__ swp,
  unsigned* __restrict__ out)
{
  __shared__ float s_items[NROWS];
  int tid = threadIdx.x;
  int row = tid >> 5, t32 = tid & 31;

  {
    unsigned pc = (unsigned)pos_cf[row];
    float psv = pos_s[row];
    unsigned neg = (unsigned)NPIX - pc, k3 = 3u*pc;
    unsigned k = pc ? (neg<k3?neg:k3) : 100u;   // pos==0 -> top-100 fallback

    unsigned bc[8]; float bsum=0.f; unsigned bcnt=0u;
    #pragma unroll
    for (int j=0;j<8;++j){
      int b = row*NBIN + t32*8 + j;
      bc[j] = ghc[b];
      bcnt += bc[j];
      bsum += ghs[b];
    }
    unsigned suf_c = bcnt; float suf_s = bsum;
    #pragma unroll
    for (int o=1;o<32;o<<=1){
      unsigned c2 = __shfl_down(suf_c, o, 32);
      float    s2 = __shfl_down(suf_s, o, 32);
      if (t32 + o < 32){ suf_c += c2; suf_s += s2; }
    }
    unsigned nxt_c = __shfl_down(suf_c, 1, 32);
    float    nxt_s = __shfl_down(suf_s, 1, 32);
    if (t32 == 31){ nxt_c = 0u; nxt_s = 0.f; }

    if (k == 0u){
      if (t32==0) s_items[row] = psv/(float)(pc?pc:1u);
    } else if (t32==0 && suf_c < k){
      float ssel = suf_s;                       // cut in zero-class tail
      s_items[row] = pc ? (psv/(float)pc + ssel/(float)k) : (ssel/100.f);
    } else if (nxt_c < k && suf_c >= k){        // owner lane
      unsigned cnt = nxt_c; float sum = nxt_s;
      int bin = -1; unsigned c0 = 1u; float sown = 0.f;
      for (int j=7;j>=0;--j){
        unsigned c = bc[j];
        if (!c) continue;
        if (cnt + c >= k){ bin = t32*8 + j; c0 = c;
                           sown = ghs[row*NBIN + bin]; break; }
        cnt += c; sum += ghs[row*NBIN + t32*8 + j];
      }
      unsigned rem = k - cnt;                   // 1 <= rem <= c0
      float mean = sown / (float)c0;
      float lo = __uint_as_float(((unsigned)bin<<6)<<16);
      float hi = __uint_as_float((((unsigned)bin+1u)<<6)<<16);
      float wdt = hi - lo;
      float mtop = mean + 0.5f*wdt*(1.f - (float)rem/(float)c0);
      mtop = fminf(fmaxf(mtop, lo), hi);        // safety clamp
      float ssel = sum + (float)rem * mtop;
      s_items[row] = pc ? (psv/(float)pc + ssel/(float)k) : (ssel/100.f);
    }
  }
  __syncthreads();
  if (tid >= 64) return;

  // ---- scalar assembly on wave 0 ----
  float v = (tid<NROWS)? s_items[tid] : 0.f;
  v = wredf_(v);                                 // lane 0 gets total
  if (tid != 0) return;

  double lsum = (double)v;
  double sw = (double)swp[0];
  double loss = (lsum/8.0)/(2.0*sw*sw + 1e-6) - log(sw);
  double d1=0.0, d2=0.0;
  for (int i=0;i<8;++i){
    d1 += (2.0*(double)segacc[2+i]  + 1e-5)/((double)segacc[10+i] + (double)segacc[18+i] + 1e-5);
    d2 += (2.0*(double)segacc[26+i] + 1e-5)/((double)segacc[34+i] + (double)segacc[42+i] + 1e-5);
  }
  double seg1 = 0.5*((double)segacc[0]/(2.0*8.0*(double)NPIX)) + (1.0 - d1/8.0);
  double seg2 = 0.5*((double)segacc[1]/(8.0*(double)NPIX))     + (1.0 - d2/8.0);
  float tot = (float)(seg1 + seg2 + loss);
  unsigned u = __float_as_uint(tot);
  unsigned h = (u + 0x7FFFu + ((u>>16)&1u)) >> 16;   // RTNE bf16 bits
  out[0] = (h<<16) | h;                               // dual f32/bf16 encoding
}

// ---------------------------------------------------------------------------
extern "C" void kernel_launch(void* const* d_in, const int* in_sizes, int n_in,
                              void* d_out, int out_size, void* d_ws, size_t ws_size,
                              hipStream_t stream)
{
  const float* us         = (const float*)d_in[0];  // (8,2,512,512)
  const float* inputs     = (const float*)d_in[1];  // (8,4,512,512)
  const float* train_mask = (const float*)d_in[2];  // (8,1,512,512)
  const float* tr_mask    = (const float*)d_in[3];  // (8,512,512,4)
  const float* label      = (const float*)d_in[4];  // (8,1,512,512)
  const float* sw         = (const float*)d_in[5];  // (1,)

  char* w = (char*)d_ws;
  size_t off = 0;
  unsigned* ghc   = (unsigned*)(w+off); off += (size_t)NROWS*NBIN*4;  // 32KB
  float*    ghs   = (float*)(w+off);    off += (size_t)NROWS*NBIN*4;  // 32KB
  float*    pos_cf= (float*)(w+off);    off += NROWS*4;
  float*    pos_s = (float*)(w+off);    off += NROWS*4;
  float*    segacc= (float*)(w+off);    off += 64*4;
  size_t zbytes = off;                               // ~66KB zeroed each call

  hipMemsetAsync(w, 0, zbytes, stream);

  k_mega <<<dim3(512),  dim3(1024), 0, stream>>>(us, inputs, train_mask, tr_mask,
                                                 label, ghc, ghs,
                                                 pos_cf, pos_s, segacc);
  k_post <<<dim3(1),    dim3(1024), 0, stream>>>(ghc, ghs, pos_cf, pos_s,
                                                 segacc, sw, (unsigned*)d_out);
}